// Round 5
// baseline (278.825 us; speedup 1.0000x reference)
//
#include <hip/hip_runtime.h>
#include <hip/hip_bf16.h>
#include <cstdint>
#include <cstddef>

// Problem constants (from reference): N=50000, E=600000, D=128, C=40, M=25000
#define DIM 128

typedef __attribute__((ext_vector_type(8))) short bf16x8;   // 8 bf16 = 4 VGPRs
typedef __attribute__((ext_vector_type(4))) float f32x4;

__device__ __forceinline__ unsigned short f2bf(float f) {
    __hip_bfloat16 h = __float2bfloat16(f);   // RN-even
    return *(unsigned short*)&h;
}
__device__ __forceinline__ unsigned pack_bf2(float a, float b) {
    return (unsigned)f2bf(a) | ((unsigned)f2bf(b) << 16);
}
// dword holding 2 bf16 -> two fp32: lo = u<<16, hi = u & 0xffff0000
__device__ __forceinline__ float bflo(unsigned u) { return __uint_as_float(u << 16); }
__device__ __forceinline__ float bfhi(unsigned u) { return __uint_as_float(u & 0xffff0000u); }

union U4B8 { uint4 q; bf16x8 v; };

// ---------------------------------------------------------------------------
// Merged init: degree count + RANK capture (blocks < egrid) + weight packing +
// sentinel zeroing + bsum-flag zeroing (blocks >= egrid).
// rank[i] = slot of edge i at its destination (atomic return) -> atomic-free
// CSR fill later.
// Wpk[(((mat*8+nt)*4+kc)*64 + lane)*8 + j] = bf16(W[k][n])
//   k = kc*32 + (lane>>4)*8 + j,  n = nt*16 + (lane&15).
// WcombP: 3 zero-padded n-tiles of Wcomb = W3@Wh [128][C] (layer-3 commute).
// whs[c] = colsum(Wh), bcomb[c] = 3*(b3@Wh)[c] + bh[c].
// Sentinels: H, H2, A row N zeroed (gathers hit them for absent slots);
// dinv[N] = 0 (weighted gather can't inject NaN from poisoned workspace).
// bsum[0..63] = 0 (lookback flags for the fused scan -- workspace is poisoned,
// so the FLAG bit must be cleared before k_scan reads it; stream order
// guarantees k_init completes first).
// ---------------------------------------------------------------------------
__global__ __launch_bounds__(256)
void k_init(const int* __restrict__ dst, int* __restrict__ count,
            int* __restrict__ rank, int e, int egrid,
            const float* __restrict__ W0, const float* __restrict__ W1,
            const float* __restrict__ W2, const float* __restrict__ W3,
            const float* __restrict__ Wh, const float* __restrict__ b3,
            const float* __restrict__ bh,
            unsigned short* __restrict__ Wpk,
            unsigned short* __restrict__ WcombP,
            float* __restrict__ whs, float* __restrict__ bcomb,
            unsigned short* __restrict__ H, unsigned short* __restrict__ H2,
            unsigned short* __restrict__ Abuf,
            float* __restrict__ dinv, int* __restrict__ bsum, int n, int C) {
    if ((int)blockIdx.x < egrid) {
        int i = blockIdx.x * 256 + threadIdx.x;
        if (i < e) rank[i] = atomicAdd(&count[dst[i]], 1);
        return;
    }
    const int NW = 4 * DIM * DIM;        // 65536
    const int NH = 3 * 4 * 64 * 8;       // 6144 (WcombP)
    const int TB = NW + NH + 64;         // tail base
    int g = (blockIdx.x - egrid) * 256 + threadIdx.x;
    if (g < NW) {
        int j   = g & 7;
        int ln  = (g >> 3) & 63;
        int kc  = (g >> 9) & 3;
        int nt  = (g >> 11) & 7;
        int mat = g >> 14;
        const float* W = (mat == 0) ? W0 : (mat == 1) ? W1 : (mat == 2) ? W2 : W3;
        int k = kc * 32 + (ln >> 4) * 8 + j;
        int nc = nt * 16 + (ln & 15);
        Wpk[g] = f2bf(W[k * DIM + nc]);
    } else if (g < NW + NH) {
        int gg = g - NW;
        int j  = gg & 7;
        int ln = (gg >> 3) & 63;
        int kc = (gg >> 9) & 3;
        int nt = gg >> 11;               // 0..2
        int k  = kc * 32 + (ln >> 4) * 8 + j;
        int nc = nt * 16 + (ln & 15);
        float s = 0.f;
        if (nc < C) {
            for (int d = 0; d < DIM; ++d) s += W3[k * DIM + d] * Wh[d * C + nc];
        }
        WcombP[gg] = f2bf(s);            // zero-padded cols >= C
    } else if (g < NW + NH + 64) {
        int c = g - NW - NH;
        if (c < C) {
            float s = 0.f, t = 0.f;
            for (int d = 0; d < DIM; ++d) {
                float w = Wh[d * C + c];
                s += w;
                t += b3[d] * w;
            }
            whs[c]   = s;
            bcomb[c] = 3.0f * t + bh[c];   // cell3 carries 3*b3
        }
    } else if (g < TB + 16) {
        int t = g - TB;
        uint4 z; z.x = z.y = z.z = z.w = 0u;
        ((uint4*)H)[(size_t)n * 16 + t] = z;      // H sentinel row
    } else if (g < TB + 32) {
        int t = g - (TB + 16);
        uint4 z; z.x = z.y = z.z = z.w = 0u;
        ((uint4*)H2)[(size_t)n * 16 + t] = z;     // H2 sentinel row
    } else if (g < TB + 48) {
        int t = g - (TB + 32);
        uint4 z; z.x = z.y = z.z = z.w = 0u;
        ((uint4*)Abuf)[(size_t)n * 16 + t] = z;   // A sentinel row
    } else if (g < TB + 112) {
        bsum[g - (TB + 48)] = 0;                  // clear lookback flags
    } else if (g == TB + 112) {
        dinv[n] = 0.f;                            // sentinel weight
    }
}

// ---------------------------------------------------------------------------
// Fused CSR scan (single kernel, decoupled lookback, +dinv fused).
// 49 blocks, trivially co-resident; each block publishes total|FLAG to bsum,
// lanes 0..nb-1 spin on PREDECESSORS only (safe even if serialized), then the
// block writes its row_ptr slice. Block-local inclusive stays in registers.
// ---------------------------------------------------------------------------
__global__ __launch_bounds__(1024)
void k_scan(const int* __restrict__ count, int* __restrict__ bsum,
            int* __restrict__ row_ptr, float* __restrict__ dinv, int n, int nb) {
    __shared__ int wsum[16];
    __shared__ int s_off;
    const int FLAG = 1 << 30;    // block totals <= E=600000 << 2^30
    int tid = threadIdx.x, lane = tid & 63, wid = tid >> 6;
    int i = blockIdx.x * 1024 + tid;
    int v = (i < n) ? count[i] : 0;
    if (i < n) dinv[i] = rsqrtf(1.0f + (float)v);   // deg includes self-loop
    int x = v;
    #pragma unroll
    for (int off = 1; off < 64; off <<= 1) {
        int y = __shfl_up(x, off, 64);
        if (lane >= off) x += y;
    }
    if (lane == 63) wsum[wid] = x;
    __syncthreads();
    int waveoff = 0, total = 0;
    #pragma unroll
    for (int w = 0; w < 16; ++w) {
        int s = wsum[w];
        if (w < wid) waveoff += s;
        total += s;
    }
    if (tid == 0) atomicExch(&bsum[blockIdx.x], total | FLAG);   // publish
    if (tid < 64) {
        int carry = 0;
        for (int base = 0; base < nb; base += 64) {
            int idx = base + tid;
            int vv = 0;
            if (idx < nb && idx < (int)blockIdx.x) {
                do { vv = atomicAdd(&bsum[idx], 0); } while (!(vv & FLAG));
                vv &= ~FLAG;
            }
            #pragma unroll
            for (int off = 32; off > 0; off >>= 1) vv += __shfl_xor(vv, off, 64);
            carry += vv;
        }
        if (tid == 0) s_off = carry;
    }
    __syncthreads();
    int off = s_off;
    if (i < n) row_ptr[i + 1] = x + waveoff + off;
    if (blockIdx.x == 0 && tid == 0) row_ptr[0] = 0;
}

// ---------------------------------------------------------------------------
// Merged: layer-0 MFMA matmul (blocks < mmg) + atomic-free CSR column fill
// (blocks >= mmg): col[row_ptr[dst]+rank] = src.
// Matmul: H'[N,128](bf16) = dinv[r]*(x @ W0). Wave = 16-row x 128-col strip:
// 8 n-tiles x 4 kc = 32 mfma_f32_16x16x32_bf16. No LDS, no barriers.
// ---------------------------------------------------------------------------
__global__ __launch_bounds__(256)
void k_fillmm(const float* __restrict__ in, const unsigned short* __restrict__ Wpk,
              const float* __restrict__ dinv, unsigned short* __restrict__ outp, int n,
              const int* __restrict__ src, const int* __restrict__ dst,
              const int* __restrict__ rank, const int* __restrict__ row_ptr,
              int* __restrict__ colv, int e, int mmg) {
    if ((int)blockIdx.x >= mmg) {
        int i = (blockIdx.x - mmg) * 256 + threadIdx.x;
        if (i < e) {
            int d = dst[i];
            int r = rank[i];
            colv[row_ptr[d] + r] = src[i];
        }
        return;
    }
    int wv   = threadIdx.x >> 6;
    int lane = threadIdx.x & 63;
    int r0   = blockIdx.x * 64 + wv * 16;
    int m    = lane & 15;
    int quad = lane >> 4;

    bf16x8 afr[4];
    int arow = r0 + m;
    bool rowok = arow < n;
    const float* ap = in + (size_t)arow * DIM + quad * 8;
    #pragma unroll
    for (int kc = 0; kc < 4; ++kc) {
        float4 p0, p1;
        if (rowok) {
            p0 = *(const float4*)(ap + kc * 32);
            p1 = *(const float4*)(ap + kc * 32 + 4);
        } else {
            p0.x = p0.y = p0.z = p0.w = 0.f;
            p1.x = p1.y = p1.z = p1.w = 0.f;
        }
        union { bf16x8 v; unsigned short u[8]; } a;
        a.u[0] = f2bf(p0.x); a.u[1] = f2bf(p0.y);
        a.u[2] = f2bf(p0.z); a.u[3] = f2bf(p0.w);
        a.u[4] = f2bf(p1.x); a.u[5] = f2bf(p1.y);
        a.u[6] = f2bf(p1.z); a.u[7] = f2bf(p1.w);
        afr[kc] = a.v;
    }

    float dsc[4];
    #pragma unroll
    for (int t = 0; t < 4; ++t) {
        int r = r0 + quad * 4 + t;
        dsc[t] = (r < n) ? dinv[r] : 0.f;
    }

    const uint4* wp = (const uint4*)Wpk;
    #pragma unroll
    for (int nt = 0; nt < 8; ++nt) {
        f32x4 acc = {0.f, 0.f, 0.f, 0.f};
        #pragma unroll
        for (int kc = 0; kc < 4; ++kc) {
            U4B8 b; b.q = wp[(nt * 4 + kc) * 64 + lane];
            acc = __builtin_amdgcn_mfma_f32_16x16x32_bf16(afr[kc], b.v, acc, 0, 0, 0);
        }
        int colb = nt * 16 + m;
        #pragma unroll
        for (int t = 0; t < 4; ++t) {
            int r = r0 + quad * 4 + t;
            if (r < n)
                outp[(size_t)r * DIM + colb] = f2bf(dsc[t] * acc[t]);
        }
    }
}

// ---------------------------------------------------------------------------
// Fused {prop + next-layer matmul}: block = 16 waves = 16 nodes (1024 thr).
// Gather is now 4-DEEP (d0..d3 in flight, j+=16): sentinel made all loads
// unconditional, removing R12's exec-mask-divergence failure mode; at avg
// quarter-degree 3 this covers the typical quarter in ONE round -> serial
// chain ~3 latencies -> ~2. TLP is capped (32 waves/CU), MLP is the lever.
// Phase 2: waves 0-7 run the next-layer MFMA, write outH prescaled.
// ---------------------------------------------------------------------------
__global__ __launch_bounds__(1024)
void k_prop_mm(const unsigned short* __restrict__ h, const int* __restrict__ row_ptr,
               const int* __restrict__ col, const float* __restrict__ dinv,
               const float* __restrict__ bias, float bscale,
               const unsigned short* addin, unsigned short* __restrict__ outp,
               const unsigned short* __restrict__ Wnext,
               unsigned short* __restrict__ outH, int n) {
    __shared__ uint4 Vs[16 * 17];    // 16 rows, stride 17 uint4 (bank-stagger)
    __shared__ float Ds[16];         // dinv per row (for outH prescale)
    int wid  = threadIdx.x >> 6;
    int lane = threadIdx.x & 63;
    int node = blockIdx.x * 16 + wid;
    bool valid = node < n;
    int gnode = valid ? node : 0;
    int beg = 0, end = 0;
    if (valid) { beg = row_ptr[gnode]; end = row_ptr[gnode + 1]; }
    float di = dinv[gnode];
    int qid = lane >> 4, fo = lane & 15;
    const uint4* h16 = (const uint4*)h;
    uint4 sd = h16[((unsigned)gnode << 4) | fo];   // self-row prefetch
    float aL0 = 0.f, aH0 = 0.f, aL1 = 0.f, aH1 = 0.f;
    float aL2 = 0.f, aH2 = 0.f, aL3 = 0.f, aH3 = 0.f;
    float bL0 = 0.f, bH0 = 0.f, bL1 = 0.f, bH1 = 0.f;
    float bL2 = 0.f, bH2 = 0.f, bL3 = 0.f, bH3 = 0.f;
    int j = beg + qid;
    int s0 = (j      < end) ? col[j]      : n;    // n = sentinel zero row
    int s1 = (j + 4  < end) ? col[j + 4]  : n;
    int s2 = (j + 8  < end) ? col[j + 8]  : n;
    int s3 = (j + 12 < end) ? col[j + 12] : n;
    while (s0 != n) {
        uint4 d0 = h16[((unsigned)s0 << 4) | fo];
        uint4 d1 = h16[((unsigned)s1 << 4) | fo];
        uint4 d2 = h16[((unsigned)s2 << 4) | fo];
        uint4 d3 = h16[((unsigned)s3 << 4) | fo];
        int jn = j + 16;
        s0 = (jn      < end) ? col[jn]      : n;
        s1 = (jn + 4  < end) ? col[jn + 4]  : n;
        s2 = (jn + 8  < end) ? col[jn + 8]  : n;
        s3 = (jn + 12 < end) ? col[jn + 12] : n;
        j = jn;
        aL0 += bflo(d0.x); aH0 += bfhi(d0.x);
        aL1 += bflo(d0.y); aH1 += bfhi(d0.y);
        aL2 += bflo(d0.z); aH2 += bfhi(d0.z);
        aL3 += bflo(d0.w); aH3 += bfhi(d0.w);
        bL0 += bflo(d1.x); bH0 += bfhi(d1.x);
        bL1 += bflo(d1.y); bH1 += bfhi(d1.y);
        bL2 += bflo(d1.z); bH2 += bfhi(d1.z);
        bL3 += bflo(d1.w); bH3 += bfhi(d1.w);
        aL0 += bflo(d2.x); aH0 += bfhi(d2.x);
        aL1 += bflo(d2.y); aH1 += bfhi(d2.y);
        aL2 += bflo(d2.z); aH2 += bfhi(d2.z);
        aL3 += bflo(d2.w); aH3 += bfhi(d2.w);
        bL0 += bflo(d3.x); bH0 += bfhi(d3.x);
        bL1 += bflo(d3.y); bH1 += bfhi(d3.y);
        bL2 += bflo(d3.z); bH2 += bfhi(d3.z);
        bL3 += bflo(d3.w); bH3 += bfhi(d3.w);
    }
    // addin-row prefetch: latency hides under the cross-quarter reduction
    uint4 av; av.x = av.y = av.z = av.w = 0u;
    if (addin) av = ((const uint4*)addin)[(size_t)gnode * 16 + fo];
    aL0 += bL0; aH0 += bH0; aL1 += bL1; aH1 += bH1;
    aL2 += bL2; aH2 += bH2; aL3 += bL3; aH3 += bH3;
    aL0 += __shfl_xor(aL0, 16, 64); aL0 += __shfl_xor(aL0, 32, 64);
    aH0 += __shfl_xor(aH0, 16, 64); aH0 += __shfl_xor(aH0, 32, 64);
    aL1 += __shfl_xor(aL1, 16, 64); aL1 += __shfl_xor(aL1, 32, 64);
    aH1 += __shfl_xor(aH1, 16, 64); aH1 += __shfl_xor(aH1, 32, 64);
    aL2 += __shfl_xor(aL2, 16, 64); aL2 += __shfl_xor(aL2, 32, 64);
    aH2 += __shfl_xor(aH2, 16, 64); aH2 += __shfl_xor(aH2, 32, 64);
    aL3 += __shfl_xor(aL3, 16, 64); aL3 += __shfl_xor(aL3, 32, 64);
    aH3 += __shfl_xor(aH3, 16, 64); aH3 += __shfl_xor(aH3, 32, 64);
    // self-loop: di^2*h[node] = di * H'[node]
    aL0 += bflo(sd.x); aH0 += bfhi(sd.x);
    aL1 += bflo(sd.y); aH1 += bfhi(sd.y);
    aL2 += bflo(sd.z); aH2 += bfhi(sd.z);
    aL3 += bflo(sd.w); aH3 += bfhi(sd.w);
    if (lane < 16) {                // fo lanes of quarter 0 finish the row
        const float4* b4 = (const float4*)bias;
        float4 bA = b4[2 * fo], bB = b4[2 * fo + 1];
        float r0x = fmaxf(fmaf(bscale, bA.x, di * aL0), 0.f);
        float r0y = fmaxf(fmaf(bscale, bA.y, di * aH0), 0.f);
        float r0z = fmaxf(fmaf(bscale, bA.z, di * aL1), 0.f);
        float r0w = fmaxf(fmaf(bscale, bA.w, di * aH1), 0.f);
        float r1x = fmaxf(fmaf(bscale, bB.x, di * aL2), 0.f);
        float r1y = fmaxf(fmaf(bscale, bB.y, di * aH2), 0.f);
        float r1z = fmaxf(fmaf(bscale, bB.z, di * aL3), 0.f);
        float r1w = fmaxf(fmaf(bscale, bB.w, di * aH3), 0.f);
        r0x += bflo(av.x); r0y += bfhi(av.x);
        r0z += bflo(av.y); r0w += bfhi(av.y);
        r1x += bflo(av.z); r1y += bfhi(av.z);
        r1z += bflo(av.w); r1w += bfhi(av.w);
        uint4 o;
        o.x = pack_bf2(r0x, r0y);
        o.y = pack_bf2(r0z, r0w);
        o.z = pack_bf2(r1x, r1y);
        o.w = pack_bf2(r1z, r1w);
        Vs[wid * 17 + fo] = o;            // feed the fused matmul
        if (valid)
            ((uint4*)outp)[(size_t)gnode * 16 + fo] = o;
        if (fo == 0) Ds[wid] = di;        // dinv of OWN row for outH
    }
    __syncthreads();   // rows staged

    // ---- phase 2: next-layer matmul on the block's 16 rows ----
    if (wid < 8) {
        int nt = wid;
        int mm = lane & 15, quad = lane >> 4;
        bf16x8 afr[4];
        #pragma unroll
        for (int kc = 0; kc < 4; ++kc) {
            U4B8 a; a.q = Vs[mm * 17 + kc * 4 + quad];
            afr[kc] = a.v;
        }
        f32x4 acc = {0.f, 0.f, 0.f, 0.f};
        const uint4* wp = (const uint4*)Wnext;
        #pragma unroll
        for (int kc = 0; kc < 4; ++kc) {
            U4B8 b; b.q = wp[(nt * 4 + kc) * 64 + lane];
            acc = __builtin_amdgcn_mfma_f32_16x16x32_bf16(afr[kc], b.v, acc, 0, 0, 0);
        }
        int colb = nt * 16 + mm;
        #pragma unroll
        for (int t = 0; t < 4; ++t) {
            int row = quad * 4 + t;
            int r = blockIdx.x * 16 + row;
            if (r < n)
                outH[(size_t)r * DIM + colb] = f2bf(Ds[row] * acc[t]);
        }
    }
}

// ---------------------------------------------------------------------------
// Plain propagation (layer 2), 4-deep gather (see k_prop_mm note).
//   cell = di*(sum_edges H'[s] + H'[node]) + bscale*bias; relu; (+addin)
// ---------------------------------------------------------------------------
__global__ __launch_bounds__(256)
void k_prop(const unsigned short* __restrict__ h, const int* __restrict__ row_ptr,
            const int* __restrict__ col, const float* __restrict__ dinv,
            const float* __restrict__ bias, float bscale,
            const unsigned short* addin, unsigned short* __restrict__ outp, int n) {
    int node = (blockIdx.x * 256 + threadIdx.x) >> 6;
    int lane = threadIdx.x & 63;
    if (node >= n) return;
    int beg = row_ptr[node], end = row_ptr[node + 1];
    float di = dinv[node];
    int qid = lane >> 4;
    int fo  = lane & 15;
    const uint4* h16 = (const uint4*)h;
    uint4 sd = h16[((unsigned)node << 4) | fo];
    float aL0 = 0.f, aH0 = 0.f, aL1 = 0.f, aH1 = 0.f;
    float aL2 = 0.f, aH2 = 0.f, aL3 = 0.f, aH3 = 0.f;
    float bL0 = 0.f, bH0 = 0.f, bL1 = 0.f, bH1 = 0.f;
    float bL2 = 0.f, bH2 = 0.f, bL3 = 0.f, bH3 = 0.f;
    int j = beg + qid;
    int s0 = (j      < end) ? col[j]      : n;
    int s1 = (j + 4  < end) ? col[j + 4]  : n;
    int s2 = (j + 8  < end) ? col[j + 8]  : n;
    int s3 = (j + 12 < end) ? col[j + 12] : n;
    while (s0 != n) {
        uint4 d0 = h16[((unsigned)s0 << 4) | fo];
        uint4 d1 = h16[((unsigned)s1 << 4) | fo];
        uint4 d2 = h16[((unsigned)s2 << 4) | fo];
        uint4 d3 = h16[((unsigned)s3 << 4) | fo];
        int jn = j + 16;
        s0 = (jn      < end) ? col[jn]      : n;
        s1 = (jn + 4  < end) ? col[jn + 4]  : n;
        s2 = (jn + 8  < end) ? col[jn + 8]  : n;
        s3 = (jn + 12 < end) ? col[jn + 12] : n;
        j = jn;
        aL0 += bflo(d0.x); aH0 += bfhi(d0.x);
        aL1 += bflo(d0.y); aH1 += bfhi(d0.y);
        aL2 += bflo(d0.z); aH2 += bfhi(d0.z);
        aL3 += bflo(d0.w); aH3 += bfhi(d0.w);
        bL0 += bflo(d1.x); bH0 += bfhi(d1.x);
        bL1 += bflo(d1.y); bH1 += bfhi(d1.y);
        bL2 += bflo(d1.z); bH2 += bfhi(d1.z);
        bL3 += bflo(d1.w); bH3 += bfhi(d1.w);
        aL0 += bflo(d2.x); aH0 += bfhi(d2.x);
        aL1 += bflo(d2.y); aH1 += bfhi(d2.y);
        aL2 += bflo(d2.z); aH2 += bfhi(d2.z);
        aL3 += bflo(d2.w); aH3 += bfhi(d2.w);
        bL0 += bflo(d3.x); bH0 += bfhi(d3.x);
        bL1 += bflo(d3.y); bH1 += bfhi(d3.y);
        bL2 += bflo(d3.z); bH2 += bfhi(d3.z);
        bL3 += bflo(d3.w); bH3 += bfhi(d3.w);
    }
    uint4 av; av.x = av.y = av.z = av.w = 0u;
    if (addin) av = ((const uint4*)addin)[(size_t)node * 16 + fo];
    aL0 += bL0; aH0 += bH0; aL1 += bL1; aH1 += bH1;
    aL2 += bL2; aH2 += bH2; aL3 += bL3; aH3 += bH3;
    aL0 += __shfl_xor(aL0, 16, 64); aL0 += __shfl_xor(aL0, 32, 64);
    aH0 += __shfl_xor(aH0, 16, 64); aH0 += __shfl_xor(aH0, 32, 64);
    aL1 += __shfl_xor(aL1, 16, 64); aL1 += __shfl_xor(aL1, 32, 64);
    aH1 += __shfl_xor(aH1, 16, 64); aH1 += __shfl_xor(aH1, 32, 64);
    aL2 += __shfl_xor(aL2, 16, 64); aL2 += __shfl_xor(aL2, 32, 64);
    aH2 += __shfl_xor(aH2, 16, 64); aH2 += __shfl_xor(aH2, 32, 64);
    aL3 += __shfl_xor(aL3, 16, 64); aL3 += __shfl_xor(aL3, 32, 64);
    aH3 += __shfl_xor(aH3, 16, 64); aH3 += __shfl_xor(aH3, 32, 64);
    aL0 += bflo(sd.x); aH0 += bfhi(sd.x);
    aL1 += bflo(sd.y); aH1 += bfhi(sd.y);
    aL2 += bflo(sd.z); aH2 += bfhi(sd.z);
    aL3 += bflo(sd.w); aH3 += bfhi(sd.w);
    if (lane < 16) {
        const float4* b4 = (const float4*)bias;
        float4 bA = b4[2 * fo], bB = b4[2 * fo + 1];
        float r0x = fmaxf(fmaf(bscale, bA.x, di * aL0), 0.f);
        float r0y = fmaxf(fmaf(bscale, bA.y, di * aH0), 0.f);
        float r0z = fmaxf(fmaf(bscale, bA.z, di * aL1), 0.f);
        float r0w = fmaxf(fmaf(bscale, bA.w, di * aH1), 0.f);
        float r1x = fmaxf(fmaf(bscale, bB.x, di * aL2), 0.f);
        float r1y = fmaxf(fmaf(bscale, bB.y, di * aH2), 0.f);
        float r1z = fmaxf(fmaf(bscale, bB.z, di * aL3), 0.f);
        float r1w = fmaxf(fmaf(bscale, bB.w, di * aH3), 0.f);
        r0x += bflo(av.x); r0y += bfhi(av.x);
        r0z += bflo(av.y); r0w += bfhi(av.y);
        r1x += bflo(av.z); r1y += bfhi(av.z);
        r1z += bflo(av.w); r1w += bfhi(av.w);
        size_t base = (size_t)node * 16 + fo;
        uint4 o;
        o.x = pack_bf2(r0x, r0y);
        o.y = pack_bf2(r0z, r0w);
        o.z = pack_bf2(r1x, r1y);
        o.w = pack_bf2(r1z, r1w);
        ((uint4*)outp)[base] = o;
    }
}

// ---------------------------------------------------------------------------
// Layer-3 commute + fused epilogue, 4-deep WEIGHTED gather.
//   S[m]   = sum_s dinv[s]*A[s] + di*A[node]
//   cell3  = di*(S@W3) + 3*b3          (logsumexp only)
//   pred   = di*(S@Wcomb) + bcomb - L*whs
// ---------------------------------------------------------------------------
__global__ __launch_bounds__(1024)
void k_propv_fused(const unsigned short* __restrict__ A, const int* __restrict__ row_ptr,
                   const int* __restrict__ col, const float* __restrict__ dinv,
                   const float* __restrict__ b3, float bscale,
                   const int* __restrict__ labels,
                   const unsigned short* __restrict__ W3pk,
                   const unsigned short* __restrict__ WcombP,
                   const float* __restrict__ whs, const float* __restrict__ bcomb,
                   float* __restrict__ outp, int m_total, int C, int n) {
    __shared__ uint4 Vs[16 * 17];
    __shared__ float Ds[16];
    __shared__ float Mred[8 * 16];
    __shared__ float Sred[8 * 16];
    __shared__ float Ls[16];
    int wid  = threadIdx.x >> 6;
    int lane = threadIdx.x & 63;
    int m = blockIdx.x * 16 + wid;
    bool valid = m < m_total;
    int node = valid ? labels[m] : 0;
    int beg = 0, end = 0;
    if (valid) { beg = row_ptr[node]; end = row_ptr[node + 1]; }
    float di = dinv[node];
    int qid = lane >> 4, fo = lane & 15;
    const uint4* h16 = (const uint4*)A;
    uint4 sd = h16[((unsigned)node << 4) | fo];
    float aL0 = 0.f, aH0 = 0.f, aL1 = 0.f, aH1 = 0.f;
    float aL2 = 0.f, aH2 = 0.f, aL3 = 0.f, aH3 = 0.f;
    float bL0 = 0.f, bH0 = 0.f, bL1 = 0.f, bH1 = 0.f;
    float bL2 = 0.f, bH2 = 0.f, bL3 = 0.f, bH3 = 0.f;
    int j = beg + qid;
    int s0 = (j      < end) ? col[j]      : n;   // dinv[n]=0, A row n zeros
    int s1 = (j + 4  < end) ? col[j + 4]  : n;
    int s2 = (j + 8  < end) ? col[j + 8]  : n;
    int s3 = (j + 12 < end) ? col[j + 12] : n;
    float w0 = dinv[s0], w1 = dinv[s1], w2 = dinv[s2], w3 = dinv[s3];
    while (s0 != n) {
        uint4 d0 = h16[((unsigned)s0 << 4) | fo];
        uint4 d1 = h16[((unsigned)s1 << 4) | fo];
        uint4 d2 = h16[((unsigned)s2 << 4) | fo];
        uint4 d3 = h16[((unsigned)s3 << 4) | fo];
        float cw0 = w0, cw1 = w1, cw2 = w2, cw3 = w3;
        int jn = j + 16;
        s0 = (jn      < end) ? col[jn]      : n;
        s1 = (jn + 4  < end) ? col[jn + 4]  : n;
        s2 = (jn + 8  < end) ? col[jn + 8]  : n;
        s3 = (jn + 12 < end) ? col[jn + 12] : n;
        w0 = dinv[s0]; w1 = dinv[s1]; w2 = dinv[s2]; w3 = dinv[s3];
        j = jn;
        aL0 = fmaf(cw0, bflo(d0.x), aL0); aH0 = fmaf(cw0, bfhi(d0.x), aH0);
        aL1 = fmaf(cw0, bflo(d0.y), aL1); aH1 = fmaf(cw0, bfhi(d0.y), aH1);
        aL2 = fmaf(cw0, bflo(d0.z), aL2); aH2 = fmaf(cw0, bfhi(d0.z), aH2);
        aL3 = fmaf(cw0, bflo(d0.w), aL3); aH3 = fmaf(cw0, bfhi(d0.w), aH3);
        bL0 = fmaf(cw1, bflo(d1.x), bL0); bH0 = fmaf(cw1, bfhi(d1.x), bH0);
        bL1 = fmaf(cw1, bflo(d1.y), bL1); bH1 = fmaf(cw1, bfhi(d1.y), bH1);
        bL2 = fmaf(cw1, bflo(d1.z), bL2); bH2 = fmaf(cw1, bfhi(d1.z), bH2);
        bL3 = fmaf(cw1, bflo(d1.w), bL3); bH3 = fmaf(cw1, bfhi(d1.w), bH3);
        aL0 = fmaf(cw2, bflo(d2.x), aL0); aH0 = fmaf(cw2, bfhi(d2.x), aH0);
        aL1 = fmaf(cw2, bflo(d2.y), aL1); aH1 = fmaf(cw2, bfhi(d2.y), aH1);
        aL2 = fmaf(cw2, bflo(d2.z), aL2); aH2 = fmaf(cw2, bfhi(d2.z), aH2);
        aL3 = fmaf(cw2, bflo(d2.w), aL3); aH3 = fmaf(cw2, bfhi(d2.w), aH3);
        bL0 = fmaf(cw3, bflo(d3.x), bL0); bH0 = fmaf(cw3, bfhi(d3.x), bH0);
        bL1 = fmaf(cw3, bflo(d3.y), bL1); bH1 = fmaf(cw3, bfhi(d3.y), bH1);
        bL2 = fmaf(cw3, bflo(d3.z), bL2); bH2 = fmaf(cw3, bfhi(d3.z), bH2);
        bL3 = fmaf(cw3, bflo(d3.w), bL3); bH3 = fmaf(cw3, bfhi(d3.w), bH3);
    }
    aL0 += bL0; aH0 += bH0; aL1 += bL1; aH1 += bH1;
    aL2 += bL2; aH2 += bH2; aL3 += bL3; aH3 += bH3;
    aL0 += __shfl_xor(aL0, 16, 64); aL0 += __shfl_xor(aL0, 32, 64);
    aH0 += __shfl_xor(aH0, 16, 64); aH0 += __shfl_xor(aH0, 32, 64);
    aL1 += __shfl_xor(aL1, 16, 64); aL1 += __shfl_xor(aL1, 32, 64);
    aH1 += __shfl_xor(aH1, 16, 64); aH1 += __shfl_xor(aH1, 32, 64);
    aL2 += __shfl_xor(aL2, 16, 64); aL2 += __shfl_xor(aL2, 32, 64);
    aH2 += __shfl_xor(aH2, 16, 64); aH2 += __shfl_xor(aH2, 32, 64);
    aL3 += __shfl_xor(aL3, 16, 64); aL3 += __shfl_xor(aL3, 32, 64);
    aH3 += __shfl_xor(aH3, 16, 64); aH3 += __shfl_xor(aH3, 32, 64);
    aL0 = fmaf(di, bflo(sd.x), aL0); aH0 = fmaf(di, bfhi(sd.x), aH0);
    aL1 = fmaf(di, bflo(sd.y), aL1); aH1 = fmaf(di, bfhi(sd.y), aH1);
    aL2 = fmaf(di, bflo(sd.z), aL2); aH2 = fmaf(di, bfhi(sd.z), aH2);
    aL3 = fmaf(di, bflo(sd.w), aL3); aH3 = fmaf(di, bfhi(sd.w), aH3);
    if (lane < 16) {
        uint4 o;
        o.x = pack_bf2(aL0, aH0);
        o.y = pack_bf2(aL1, aH1);
        o.z = pack_bf2(aL2, aH2);
        o.w = pack_bf2(aL3, aH3);
        Vs[wid * 17 + fo] = o;
    }
    if (lane == 0) Ds[wid] = di;
    __syncthreads();   // barrier 1: S staged

    f32x4 hacc = {0.f, 0.f, 0.f, 0.f};
    float cell[4] = {0.f, 0.f, 0.f, 0.f};
    float gmx[4]  = {0.f, 0.f, 0.f, 0.f};
    int mm = lane & 15, quad = lane >> 4;
    if (wid < 8) {
        int nt = wid;
        bf16x8 afr[4];
        #pragma unroll
        for (int kc = 0; kc < 4; ++kc) {
            U4B8 a; a.q = Vs[mm * 17 + kc * 4 + quad];
            afr[kc] = a.v;
        }
        f32x4 acc = {0.f, 0.f, 0.f, 0.f};
        const uint4* wp = (const uint4*)W3pk;
        #pragma unroll
        for (int kc = 0; kc < 4; ++kc) {
            U4B8 b; b.q = wp[(nt * 4 + kc) * 64 + lane];
            acc = __builtin_amdgcn_mfma_f32_16x16x32_bf16(afr[kc], b.v, acc, 0, 0, 0);
        }
        float b3c = bscale * b3[nt * 16 + mm];
        #pragma unroll
        for (int t = 0; t < 4; ++t) {
            int row = quad * 4 + t;
            cell[t] = fmaf(Ds[row], acc[t], b3c);
            float mxv = cell[t];
            #pragma unroll
            for (int off = 1; off < 16; off <<= 1)
                mxv = fmaxf(mxv, __shfl_xor(mxv, off, 64));
            if (mm == 0) Mred[nt * 16 + row] = mxv;
        }
    } else if (wid < 11) {
        int nth = wid - 8;
        bf16x8 afr[4];
        #pragma unroll
        for (int kc = 0; kc < 4; ++kc) {
            U4B8 a; a.q = Vs[mm * 17 + kc * 4 + quad];
            afr[kc] = a.v;
        }
        const uint4* wp = (const uint4*)WcombP;
        #pragma unroll
        for (int kc = 0; kc < 4; ++kc) {
            U4B8 b; b.q = wp[(nth * 4 + kc) * 64 + lane];
            hacc = __builtin_amdgcn_mfma_f32_16x16x32_bf16(afr[kc], b.v, hacc, 0, 0, 0);
        }
    }
    __syncthreads();   // barrier 2: Mred complete

    if (wid < 8) {
        int nt = wid;
        #pragma unroll
        for (int t = 0; t < 4; ++t) {
            int row = quad * 4 + t;
            float g = Mred[row];
            #pragma unroll
            for (int i = 1; i < 8; ++i) g = fmaxf(g, Mred[i * 16 + row]);
            gmx[t] = g;
            float e = expf(cell[t] - g);
            #pragma unroll
            for (int off = 1; off < 16; off <<= 1) e += __shfl_xor(e, off, 64);
            if (mm == 0) Sred[nt * 16 + row] = e;
        }
    }
    __syncthreads();   // barrier 3: Sred complete

    if (wid == 0 && mm == 0) {
        #pragma unroll
        for (int t = 0; t < 4; ++t) {
            int row = quad * 4 + t;
            float s = Sred[row];
            #pragma unroll
            for (int i = 1; i < 8; ++i) s += Sred[i * 16 + row];
            Ls[row] = gmx[t] + logf(s);
        }
    }
    __syncthreads();   // barrier 4: Ls ready

    if (wid >= 8 && wid < 11) {
        int nth = wid - 8;
        int colc = nth * 16 + mm;
        if (colc < C) {
            float wsc = whs[colc], bc = bcomb[colc];
            #pragma unroll
            for (int t = 0; t < 4; ++t) {
                int row = quad * 4 + t;
                int r = blockIdx.x * 16 + row;
                if (r < m_total)
                    outp[(size_t)r * C + colc] =
                        fmaf(Ds[row], hacc[t], bc) - Ls[row] * wsc;
            }
        }
    }
}

// ---------------------------------------------------------------------------
extern "C" void kernel_launch(void* const* d_in, const int* in_sizes, int n_in,
                              void* d_out, int out_size, void* d_ws, size_t ws_size,
                              hipStream_t stream) {
    const float* x      = (const float*)d_in[0];
    const int*   edges  = (const int*)d_in[1];
    const int*   labels = (const int*)d_in[2];
    const float* W0 = (const float*)d_in[3];
    const float* b0 = (const float*)d_in[4];
    const float* W1 = (const float*)d_in[5];
    const float* b1 = (const float*)d_in[6];
    const float* W2 = (const float*)d_in[7];
    const float* b2 = (const float*)d_in[8];
    const float* W3 = (const float*)d_in[9];
    const float* b3 = (const float*)d_in[10];
    const float* Wh = (const float*)d_in[11];
    const float* bh = (const float*)d_in[12];
    float* out = (float*)d_out;

    const int N = in_sizes[0] / DIM;       // 50000
    const int E = in_sizes[1] / 2;         // 600000
    const int M = in_sizes[2];             // 25000
    const int C = in_sizes[12];            // 40

    // Workspace layout (256B-aligned slices)
    char* ws = (char*)d_ws;
    auto alloc = [&](size_t bytes) {
        char* p = ws;
        ws += (bytes + 255) & ~(size_t)255;
        return p;
    };
    float* dinv    = (float*)alloc((size_t)(N + 1) * 4);   // +1: sentinel weight 0
    int*   count   = (int*)  alloc((size_t)N * 4);
    int*   row_ptr = (int*)  alloc((size_t)(N + 1) * 4);
    int*   rank    = (int*)  alloc((size_t)E * 4);
    int*   bsum    = (int*)  alloc(64 * 4);
    int*   col     = (int*)  alloc((size_t)E * 4);
    float* whs     = (float*)alloc(256);
    float* bcomb   = (float*)alloc(256);
    unsigned short* Wpk    = (unsigned short*)alloc((size_t)4 * DIM * DIM * 2);  // packed W0..3
    unsigned short* WcombP = (unsigned short*)alloc((size_t)3 * 4 * 64 * 8 * 2); // packed W3@Wh
    unsigned short* H   = (unsigned short*)alloc((size_t)(N + 1) * DIM * 2);  // bf16 ping + sentinel
    unsigned short* H2  = (unsigned short*)alloc((size_t)(N + 1) * DIM * 2);  // bf16 pong + sentinel
    unsigned short* R0  = (unsigned short*)alloc((size_t)N * DIM * 2);        // relu(cell0) bf16
    unsigned short* A   = (unsigned short*)alloc((size_t)(N + 1) * DIM * 2);  // running relu-sum + sentinel

    const int* src = edges;
    const int* dst = edges + E;

    int egrid  = (E + 255) / 256;
    int sgrid  = (N + 1023) / 1024;        // scan blocks (49 for N=50000)
    int mmgrid = (N + 63) / 64;            // 64-row strips, 4 waves/block
    int pgrid  = (N + 3) / 4;              // one wave per node, 4 waves/block
    int fgrid  = (N + 15) / 16;            // fused prop+mm blocks (16 nodes each)
    const int FR = DIM * DIM;              // per-matrix packed elements
    const int NPACK = 4 * FR + 3 * 4 * 64 * 8 + 64 + 113;
    int packgrid = (NPACK + 255) / 256;

    // --- CSR build + weight packing (count+rank || pack, fill || matmul0) ---
    hipMemsetAsync(count, 0, (size_t)N * 4, stream);
    k_init <<<egrid + packgrid, 256, 0, stream>>>(dst, count, rank, E, egrid,
                                                  W0, W1, W2, W3, Wh, b3, bh,
                                                  Wpk, WcombP, whs, bcomb,
                                                  H, H2, A, dinv, bsum, N, C);
    k_scan <<<sgrid, 1024, 0, stream>>>(count, bsum, row_ptr, dinv, N, sgrid);
    k_fillmm<<<mmgrid + egrid, 256, 0, stream>>>(x, Wpk, dinv, H, N,
                                                 src, dst, rank, row_ptr, col, E, mmgrid);
    // --- P0: R0 = relu(Â(xW0)+b0); fused mm1 -> H2 = dinv*(R0@W1) ---
    k_prop_mm<<<fgrid, 1024, 0, stream>>>(H, row_ptr, col, dinv, b0, 1.f,
                                          nullptr, R0, Wpk + 1 * FR, H2, N);
    // --- P1: A = R0 + relu(Â(R0W1)+b1); fused mm2 -> H = dinv*(A@W2) ---
    k_prop_mm<<<fgrid, 1024, 0, stream>>>(H2, row_ptr, col, dinv, b1, 1.f,
                                          R0, A, Wpk + 2 * FR, H, N);
    // --- P2: A += relu(Â(AW2)+2b2)  (in-place row-local, no trailing mm) ---
    k_prop    <<<pgrid, 256, 0, stream>>>(H, row_ptr, col, dinv, b2, 2.f, A, A, N);
    // --- layer-3 commute: gather A directly (weighted), matmul only M rows ---
    k_propv_fused<<<(M + 15) / 16, 1024, 0, stream>>>(A, row_ptr, col, dinv, b3, 3.f,
                                                      labels, Wpk + 3 * FR, WcombP,
                                                      whs, bcomb, out, M, C, N);
}

// Round 6
// 267.873 us; speedup vs baseline: 1.0409x; 1.0409x over previous
//
#include <hip/hip_runtime.h>
#include <hip/hip_bf16.h>
#include <cstdint>
#include <cstddef>

// Problem constants (from reference): N=50000, E=600000, D=128, C=40, M=25000
#define DIM 128

typedef __attribute__((ext_vector_type(8))) short bf16x8;   // 8 bf16 = 4 VGPRs
typedef __attribute__((ext_vector_type(4))) float f32x4;

__device__ __forceinline__ unsigned short f2bf(float f) {
    __hip_bfloat16 h = __float2bfloat16(f);   // RN-even
    return *(unsigned short*)&h;
}
__device__ __forceinline__ unsigned pack_bf2(float a, float b) {
    return (unsigned)f2bf(a) | ((unsigned)f2bf(b) << 16);
}
// dword holding 2 bf16 -> two fp32: lo = u<<16, hi = u & 0xffff0000
__device__ __forceinline__ float bflo(unsigned u) { return __uint_as_float(u << 16); }
__device__ __forceinline__ float bfhi(unsigned u) { return __uint_as_float(u & 0xffff0000u); }

union U4B8 { uint4 q; bf16x8 v; };

// ---------------------------------------------------------------------------
// Merged init: degree count + RANK capture (blocks < egrid) + weight packing +
// sentinel zeroing + bsum-flag zeroing (blocks >= egrid).
// rank[i] = slot of edge i at its destination (atomic return) -> atomic-free
// CSR fill later.
// Wpk[(((mat*8+nt)*4+kc)*64 + lane)*8 + j] = bf16(W[k][n])
//   k = kc*32 + (lane>>4)*8 + j,  n = nt*16 + (lane&15).
// WcombP: 3 zero-padded n-tiles of Wcomb = W3@Wh [128][C] (layer-3 commute).
// whs[c] = colsum(Wh), bcomb[c] = 3*(b3@Wh)[c] + bh[c].
// Sentinels: H, H2, A row N zeroed; dinv[N] = 0; bsum[0..63] = 0 (lookback
// flags; workspace is poisoned, stream order guarantees k_init runs first).
// ---------------------------------------------------------------------------
__global__ __launch_bounds__(256)
void k_init(const int* __restrict__ dst, int* __restrict__ count,
            int* __restrict__ rank, int e, int egrid,
            const float* __restrict__ W0, const float* __restrict__ W1,
            const float* __restrict__ W2, const float* __restrict__ W3,
            const float* __restrict__ Wh, const float* __restrict__ b3,
            const float* __restrict__ bh,
            unsigned short* __restrict__ Wpk,
            unsigned short* __restrict__ WcombP,
            float* __restrict__ whs, float* __restrict__ bcomb,
            unsigned short* __restrict__ H, unsigned short* __restrict__ H2,
            unsigned short* __restrict__ Abuf,
            float* __restrict__ dinv, int* __restrict__ bsum, int n, int C) {
    if ((int)blockIdx.x < egrid) {
        int i = blockIdx.x * 256 + threadIdx.x;
        if (i < e) rank[i] = atomicAdd(&count[dst[i]], 1);
        return;
    }
    const int NW = 4 * DIM * DIM;        // 65536
    const int NH = 3 * 4 * 64 * 8;       // 6144 (WcombP)
    const int TB = NW + NH + 64;         // tail base
    int g = (blockIdx.x - egrid) * 256 + threadIdx.x;
    if (g < NW) {
        int j   = g & 7;
        int ln  = (g >> 3) & 63;
        int kc  = (g >> 9) & 3;
        int nt  = (g >> 11) & 7;
        int mat = g >> 14;
        const float* W = (mat == 0) ? W0 : (mat == 1) ? W1 : (mat == 2) ? W2 : W3;
        int k = kc * 32 + (ln >> 4) * 8 + j;
        int nc = nt * 16 + (ln & 15);
        Wpk[g] = f2bf(W[k * DIM + nc]);
    } else if (g < NW + NH) {
        int gg = g - NW;
        int j  = gg & 7;
        int ln = (gg >> 3) & 63;
        int kc = (gg >> 9) & 3;
        int nt = gg >> 11;               // 0..2
        int k  = kc * 32 + (ln >> 4) * 8 + j;
        int nc = nt * 16 + (ln & 15);
        float s = 0.f;
        if (nc < C) {
            for (int d = 0; d < DIM; ++d) s += W3[k * DIM + d] * Wh[d * C + nc];
        }
        WcombP[gg] = f2bf(s);            // zero-padded cols >= C
    } else if (g < NW + NH + 64) {
        int c = g - NW - NH;
        if (c < C) {
            float s = 0.f, t = 0.f;
            for (int d = 0; d < DIM; ++d) {
                float w = Wh[d * C + c];
                s += w;
                t += b3[d] * w;
            }
            whs[c]   = s;
            bcomb[c] = 3.0f * t + bh[c];   // cell3 carries 3*b3
        }
    } else if (g < TB + 16) {
        int t = g - TB;
        uint4 z; z.x = z.y = z.z = z.w = 0u;
        ((uint4*)H)[(size_t)n * 16 + t] = z;      // H sentinel row
    } else if (g < TB + 32) {
        int t = g - (TB + 16);
        uint4 z; z.x = z.y = z.z = z.w = 0u;
        ((uint4*)H2)[(size_t)n * 16 + t] = z;     // H2 sentinel row
    } else if (g < TB + 48) {
        int t = g - (TB + 32);
        uint4 z; z.x = z.y = z.z = z.w = 0u;
        ((uint4*)Abuf)[(size_t)n * 16 + t] = z;   // A sentinel row
    } else if (g < TB + 112) {
        bsum[g - (TB + 48)] = 0;                  // clear lookback flags
    } else if (g == TB + 112) {
        dinv[n] = 0.f;                            // sentinel weight
    }
}

// ---------------------------------------------------------------------------
// Fused CSR scan (single kernel, decoupled lookback, +dinv fused).
// 49 blocks; each publishes total|FLAG to bsum, lanes spin on PREDECESSORS
// only (safe even if serialized), then the block writes its row_ptr slice.
// ---------------------------------------------------------------------------
__global__ __launch_bounds__(1024)
void k_scan(const int* __restrict__ count, int* __restrict__ bsum,
            int* __restrict__ row_ptr, float* __restrict__ dinv, int n, int nb) {
    __shared__ int wsum[16];
    __shared__ int s_off;
    const int FLAG = 1 << 30;    // block totals <= E=600000 << 2^30
    int tid = threadIdx.x, lane = tid & 63, wid = tid >> 6;
    int i = blockIdx.x * 1024 + tid;
    int v = (i < n) ? count[i] : 0;
    if (i < n) dinv[i] = rsqrtf(1.0f + (float)v);   // deg includes self-loop
    int x = v;
    #pragma unroll
    for (int off = 1; off < 64; off <<= 1) {
        int y = __shfl_up(x, off, 64);
        if (lane >= off) x += y;
    }
    if (lane == 63) wsum[wid] = x;
    __syncthreads();
    int waveoff = 0, total = 0;
    #pragma unroll
    for (int w = 0; w < 16; ++w) {
        int s = wsum[w];
        if (w < wid) waveoff += s;
        total += s;
    }
    if (tid == 0) atomicExch(&bsum[blockIdx.x], total | FLAG);   // publish
    if (tid < 64) {
        int carry = 0;
        for (int base = 0; base < nb; base += 64) {
            int idx = base + tid;
            int vv = 0;
            if (idx < nb && idx < (int)blockIdx.x) {
                do { vv = atomicAdd(&bsum[idx], 0); } while (!(vv & FLAG));
                vv &= ~FLAG;
            }
            #pragma unroll
            for (int off = 32; off > 0; off >>= 1) vv += __shfl_xor(vv, off, 64);
            carry += vv;
        }
        if (tid == 0) s_off = carry;
    }
    __syncthreads();
    int off = s_off;
    if (i < n) row_ptr[i + 1] = x + waveoff + off;
    if (blockIdx.x == 0 && tid == 0) row_ptr[0] = 0;
}

// ---------------------------------------------------------------------------
// Merged: layer-0 MFMA matmul (blocks < mmg) + atomic-free CSR column fill
// (blocks >= mmg): col[row_ptr[dst]+rank] = src.
// Matmul: H'[N,128](bf16) = dinv[r]*(x @ W0). Wave = 16-row x 128-col strip:
// 8 n-tiles x 4 kc = 32 mfma_f32_16x16x32_bf16. No LDS, no barriers.
// ---------------------------------------------------------------------------
__global__ __launch_bounds__(256)
void k_fillmm(const float* __restrict__ in, const unsigned short* __restrict__ Wpk,
              const float* __restrict__ dinv, unsigned short* __restrict__ outp, int n,
              const int* __restrict__ src, const int* __restrict__ dst,
              const int* __restrict__ rank, const int* __restrict__ row_ptr,
              int* __restrict__ colv, int e, int mmg) {
    if ((int)blockIdx.x >= mmg) {
        int i = (blockIdx.x - mmg) * 256 + threadIdx.x;
        if (i < e) {
            int d = dst[i];
            int r = rank[i];
            colv[row_ptr[d] + r] = src[i];
        }
        return;
    }
    int wv   = threadIdx.x >> 6;
    int lane = threadIdx.x & 63;
    int r0   = blockIdx.x * 64 + wv * 16;
    int m    = lane & 15;
    int quad = lane >> 4;

    bf16x8 afr[4];
    int arow = r0 + m;
    bool rowok = arow < n;
    const float* ap = in + (size_t)arow * DIM + quad * 8;
    #pragma unroll
    for (int kc = 0; kc < 4; ++kc) {
        float4 p0, p1;
        if (rowok) {
            p0 = *(const float4*)(ap + kc * 32);
            p1 = *(const float4*)(ap + kc * 32 + 4);
        } else {
            p0.x = p0.y = p0.z = p0.w = 0.f;
            p1.x = p1.y = p1.z = p1.w = 0.f;
        }
        union { bf16x8 v; unsigned short u[8]; } a;
        a.u[0] = f2bf(p0.x); a.u[1] = f2bf(p0.y);
        a.u[2] = f2bf(p0.z); a.u[3] = f2bf(p0.w);
        a.u[4] = f2bf(p1.x); a.u[5] = f2bf(p1.y);
        a.u[6] = f2bf(p1.z); a.u[7] = f2bf(p1.w);
        afr[kc] = a.v;
    }

    float dsc[4];
    #pragma unroll
    for (int t = 0; t < 4; ++t) {
        int r = r0 + quad * 4 + t;
        dsc[t] = (r < n) ? dinv[r] : 0.f;
    }

    const uint4* wp = (const uint4*)Wpk;
    #pragma unroll
    for (int nt = 0; nt < 8; ++nt) {
        f32x4 acc = {0.f, 0.f, 0.f, 0.f};
        #pragma unroll
        for (int kc = 0; kc < 4; ++kc) {
            U4B8 b; b.q = wp[(nt * 4 + kc) * 64 + lane];
            acc = __builtin_amdgcn_mfma_f32_16x16x32_bf16(afr[kc], b.v, acc, 0, 0, 0);
        }
        int colb = nt * 16 + m;
        #pragma unroll
        for (int t = 0; t < 4; ++t) {
            int r = r0 + quad * 4 + t;
            if (r < n)
                outp[(size_t)r * DIM + colb] = f2bf(dsc[t] * acc[t]);
        }
    }
}

// ---------------------------------------------------------------------------
// Fused {prop + next-layer matmul}: block = 16 waves = 16 nodes (1024 thr).
// Gather: quarter-wave, 2-DEEP pipeline, sentinel zero row, prefetched
// self-row/addin. [GATHER DEPTH IS FINAL AT 2 — 4-deep regressed THREE times
// (R10 bug, R12 354us, R5-this-session 269->279 even with sentinel-
// unconditional loads). The gathers are L2-miss-traffic/balance bound, not
// MLP bound; deeper pipelines only add VGPR + unroll overhead.]
// Phase 2: waves 0-7 run the next-layer MFMA, write outH prescaled.
// outH must differ from h (ping-pong H/H2): other blocks still gather h.
// ---------------------------------------------------------------------------
__global__ __launch_bounds__(1024)
void k_prop_mm(const unsigned short* __restrict__ h, const int* __restrict__ row_ptr,
               const int* __restrict__ col, const float* __restrict__ dinv,
               const float* __restrict__ bias, float bscale,
               const unsigned short* addin, unsigned short* __restrict__ outp,
               const unsigned short* __restrict__ Wnext,
               unsigned short* __restrict__ outH, int n) {
    __shared__ uint4 Vs[16 * 17];    // 16 rows, stride 17 uint4 (bank-stagger)
    __shared__ float Ds[16];         // dinv per row (for outH prescale)
    int wid  = threadIdx.x >> 6;
    int lane = threadIdx.x & 63;
    int node = blockIdx.x * 16 + wid;
    bool valid = node < n;
    int gnode = valid ? node : 0;
    int beg = 0, end = 0;
    if (valid) { beg = row_ptr[gnode]; end = row_ptr[gnode + 1]; }
    float di = dinv[gnode];
    int qid = lane >> 4, fo = lane & 15;
    const uint4* h16 = (const uint4*)h;
    uint4 sd = h16[((unsigned)gnode << 4) | fo];   // self-row prefetch
    float aL0 = 0.f, aH0 = 0.f, aL1 = 0.f, aH1 = 0.f;
    float aL2 = 0.f, aH2 = 0.f, aL3 = 0.f, aH3 = 0.f;
    float bL0 = 0.f, bH0 = 0.f, bL1 = 0.f, bH1 = 0.f;
    float bL2 = 0.f, bH2 = 0.f, bL3 = 0.f, bH3 = 0.f;
    int j = beg + qid;
    int s0 = (j < end) ? col[j] : n;         // n = sentinel zero row
    int s1 = (j + 4 < end) ? col[j + 4] : n;
    while (s0 != n) {
        uint4 d0 = h16[((unsigned)s0 << 4) | fo];
        uint4 d1 = h16[((unsigned)s1 << 4) | fo];   // sentinel -> exact zeros
        int jn = j + 8;
        s0 = (jn < end) ? col[jn] : n;              // prefetch next pair
        s1 = (jn + 4 < end) ? col[jn + 4] : n;
        j = jn;
        aL0 += bflo(d0.x); aH0 += bfhi(d0.x);
        aL1 += bflo(d0.y); aH1 += bfhi(d0.y);
        aL2 += bflo(d0.z); aH2 += bfhi(d0.z);
        aL3 += bflo(d0.w); aH3 += bfhi(d0.w);
        bL0 += bflo(d1.x); bH0 += bfhi(d1.x);
        bL1 += bflo(d1.y); bH1 += bfhi(d1.y);
        bL2 += bflo(d1.z); bH2 += bfhi(d1.z);
        bL3 += bflo(d1.w); bH3 += bfhi(d1.w);
    }
    // addin-row prefetch: latency hides under the cross-quarter reduction
    uint4 av; av.x = av.y = av.z = av.w = 0u;
    if (addin) av = ((const uint4*)addin)[(size_t)gnode * 16 + fo];
    aL0 += bL0; aH0 += bH0; aL1 += bL1; aH1 += bH1;
    aL2 += bL2; aH2 += bH2; aL3 += bL3; aH3 += bH3;
    aL0 += __shfl_xor(aL0, 16, 64); aL0 += __shfl_xor(aL0, 32, 64);
    aH0 += __shfl_xor(aH0, 16, 64); aH0 += __shfl_xor(aH0, 32, 64);
    aL1 += __shfl_xor(aL1, 16, 64); aL1 += __shfl_xor(aL1, 32, 64);
    aH1 += __shfl_xor(aH1, 16, 64); aH1 += __shfl_xor(aH1, 32, 64);
    aL2 += __shfl_xor(aL2, 16, 64); aL2 += __shfl_xor(aL2, 32, 64);
    aH2 += __shfl_xor(aH2, 16, 64); aH2 += __shfl_xor(aH2, 32, 64);
    aL3 += __shfl_xor(aL3, 16, 64); aL3 += __shfl_xor(aL3, 32, 64);
    aH3 += __shfl_xor(aH3, 16, 64); aH3 += __shfl_xor(aH3, 32, 64);
    // self-loop: di^2*h[node] = di * H'[node]
    aL0 += bflo(sd.x); aH0 += bfhi(sd.x);
    aL1 += bflo(sd.y); aH1 += bfhi(sd.y);
    aL2 += bflo(sd.z); aH2 += bfhi(sd.z);
    aL3 += bflo(sd.w); aH3 += bfhi(sd.w);
    if (lane < 16) {                // fo lanes of quarter 0 finish the row
        const float4* b4 = (const float4*)bias;
        float4 bA = b4[2 * fo], bB = b4[2 * fo + 1];
        float r0x = fmaxf(fmaf(bscale, bA.x, di * aL0), 0.f);
        float r0y = fmaxf(fmaf(bscale, bA.y, di * aH0), 0.f);
        float r0z = fmaxf(fmaf(bscale, bA.z, di * aL1), 0.f);
        float r0w = fmaxf(fmaf(bscale, bA.w, di * aH1), 0.f);
        float r1x = fmaxf(fmaf(bscale, bB.x, di * aL2), 0.f);
        float r1y = fmaxf(fmaf(bscale, bB.y, di * aH2), 0.f);
        float r1z = fmaxf(fmaf(bscale, bB.z, di * aL3), 0.f);
        float r1w = fmaxf(fmaf(bscale, bB.w, di * aH3), 0.f);
        r0x += bflo(av.x); r0y += bfhi(av.x);
        r0z += bflo(av.y); r0w += bfhi(av.y);
        r1x += bflo(av.z); r1y += bfhi(av.z);
        r1z += bflo(av.w); r1w += bfhi(av.w);
        uint4 o;
        o.x = pack_bf2(r0x, r0y);
        o.y = pack_bf2(r0z, r0w);
        o.z = pack_bf2(r1x, r1y);
        o.w = pack_bf2(r1z, r1w);
        Vs[wid * 17 + fo] = o;            // feed the fused matmul
        if (valid)
            ((uint4*)outp)[(size_t)gnode * 16 + fo] = o;
        if (fo == 0) Ds[wid] = di;        // dinv of OWN row for outH
    }
    __syncthreads();   // rows staged

    // ---- phase 2: next-layer matmul on the block's 16 rows ----
    if (wid < 8) {
        int nt = wid;
        int mm = lane & 15, quad = lane >> 4;
        bf16x8 afr[4];
        #pragma unroll
        for (int kc = 0; kc < 4; ++kc) {
            U4B8 a; a.q = Vs[mm * 17 + kc * 4 + quad];
            afr[kc] = a.v;
        }
        f32x4 acc = {0.f, 0.f, 0.f, 0.f};
        const uint4* wp = (const uint4*)Wnext;
        #pragma unroll
        for (int kc = 0; kc < 4; ++kc) {
            U4B8 b; b.q = wp[(nt * 4 + kc) * 64 + lane];
            acc = __builtin_amdgcn_mfma_f32_16x16x32_bf16(afr[kc], b.v, acc, 0, 0, 0);
        }
        int colb = nt * 16 + mm;
        #pragma unroll
        for (int t = 0; t < 4; ++t) {
            int row = quad * 4 + t;
            int r = blockIdx.x * 16 + row;
            if (r < n)
                outH[(size_t)r * DIM + colb] = f2bf(Ds[row] * acc[t]);
        }
    }
}

// ---------------------------------------------------------------------------
// Plain propagation (layer 2), 2-deep gather (depth FINAL, see k_prop_mm).
//   cell = di*(sum_edges H'[s] + H'[node]) + bscale*bias; relu; (+addin)
// addin==outp (in-place) allowed: each wave only touches its own row.
// ---------------------------------------------------------------------------
__global__ __launch_bounds__(256)
void k_prop(const unsigned short* __restrict__ h, const int* __restrict__ row_ptr,
            const int* __restrict__ col, const float* __restrict__ dinv,
            const float* __restrict__ bias, float bscale,
            const unsigned short* addin, unsigned short* __restrict__ outp, int n) {
    int node = (blockIdx.x * 256 + threadIdx.x) >> 6;
    int lane = threadIdx.x & 63;
    if (node >= n) return;
    int beg = row_ptr[node], end = row_ptr[node + 1];
    float di = dinv[node];
    int qid = lane >> 4;
    int fo  = lane & 15;
    const uint4* h16 = (const uint4*)h;
    uint4 sd = h16[((unsigned)node << 4) | fo];
    float aL0 = 0.f, aH0 = 0.f, aL1 = 0.f, aH1 = 0.f;
    float aL2 = 0.f, aH2 = 0.f, aL3 = 0.f, aH3 = 0.f;
    float bL0 = 0.f, bH0 = 0.f, bL1 = 0.f, bH1 = 0.f;
    float bL2 = 0.f, bH2 = 0.f, bL3 = 0.f, bH3 = 0.f;
    int j = beg + qid;
    int s0 = (j < end) ? col[j] : n;
    int s1 = (j + 4 < end) ? col[j + 4] : n;
    while (s0 != n) {
        uint4 d0 = h16[((unsigned)s0 << 4) | fo];
        uint4 d1 = h16[((unsigned)s1 << 4) | fo];
        int jn = j + 8;
        s0 = (jn < end) ? col[jn] : n;
        s1 = (jn + 4 < end) ? col[jn + 4] : n;
        j = jn;
        aL0 += bflo(d0.x); aH0 += bfhi(d0.x);
        aL1 += bflo(d0.y); aH1 += bfhi(d0.y);
        aL2 += bflo(d0.z); aH2 += bfhi(d0.z);
        aL3 += bflo(d0.w); aH3 += bfhi(d0.w);
        bL0 += bflo(d1.x); bH0 += bfhi(d1.x);
        bL1 += bflo(d1.y); bH1 += bfhi(d1.y);
        bL2 += bflo(d1.z); bH2 += bfhi(d1.z);
        bL3 += bflo(d1.w); bH3 += bfhi(d1.w);
    }
    uint4 av; av.x = av.y = av.z = av.w = 0u;
    if (addin) av = ((const uint4*)addin)[(size_t)node * 16 + fo];
    aL0 += bL0; aH0 += bH0; aL1 += bL1; aH1 += bH1;
    aL2 += bL2; aH2 += bH2; aL3 += bL3; aH3 += bH3;
    aL0 += __shfl_xor(aL0, 16, 64); aL0 += __shfl_xor(aL0, 32, 64);
    aH0 += __shfl_xor(aH0, 16, 64); aH0 += __shfl_xor(aH0, 32, 64);
    aL1 += __shfl_xor(aL1, 16, 64); aL1 += __shfl_xor(aL1, 32, 64);
    aH1 += __shfl_xor(aH1, 16, 64); aH1 += __shfl_xor(aH1, 32, 64);
    aL2 += __shfl_xor(aL2, 16, 64); aL2 += __shfl_xor(aL2, 32, 64);
    aH2 += __shfl_xor(aH2, 16, 64); aH2 += __shfl_xor(aH2, 32, 64);
    aL3 += __shfl_xor(aL3, 16, 64); aL3 += __shfl_xor(aL3, 32, 64);
    aH3 += __shfl_xor(aH3, 16, 64); aH3 += __shfl_xor(aH3, 32, 64);
    aL0 += bflo(sd.x); aH0 += bfhi(sd.x);
    aL1 += bflo(sd.y); aH1 += bfhi(sd.y);
    aL2 += bflo(sd.z); aH2 += bfhi(sd.z);
    aL3 += bflo(sd.w); aH3 += bfhi(sd.w);
    if (lane < 16) {
        const float4* b4 = (const float4*)bias;
        float4 bA = b4[2 * fo], bB = b4[2 * fo + 1];
        float r0x = fmaxf(fmaf(bscale, bA.x, di * aL0), 0.f);
        float r0y = fmaxf(fmaf(bscale, bA.y, di * aH0), 0.f);
        float r0z = fmaxf(fmaf(bscale, bA.z, di * aL1), 0.f);
        float r0w = fmaxf(fmaf(bscale, bA.w, di * aH1), 0.f);
        float r1x = fmaxf(fmaf(bscale, bB.x, di * aL2), 0.f);
        float r1y = fmaxf(fmaf(bscale, bB.y, di * aH2), 0.f);
        float r1z = fmaxf(fmaf(bscale, bB.z, di * aL3), 0.f);
        float r1w = fmaxf(fmaf(bscale, bB.w, di * aH3), 0.f);
        r0x += bflo(av.x); r0y += bfhi(av.x);
        r0z += bflo(av.y); r0w += bfhi(av.y);
        r1x += bflo(av.z); r1y += bfhi(av.z);
        r1z += bflo(av.w); r1w += bfhi(av.w);
        size_t base = (size_t)node * 16 + fo;
        uint4 o;
        o.x = pack_bf2(r0x, r0y);
        o.y = pack_bf2(r0z, r0w);
        o.z = pack_bf2(r1x, r1y);
        o.w = pack_bf2(r1z, r1w);
        ((uint4*)outp)[base] = o;
    }
}

// ---------------------------------------------------------------------------
// Layer-3 commute + fused epilogue, 2-deep WEIGHTED gather (depth FINAL).
//   S[m]   = sum_s dinv[s]*A[s] + di*A[node]
//   cell3  = di*(S@W3) + 3*b3          (logsumexp only)
//   pred   = di*(S@Wcomb) + bcomb - L*whs
// ---------------------------------------------------------------------------
__global__ __launch_bounds__(1024)
void k_propv_fused(const unsigned short* __restrict__ A, const int* __restrict__ row_ptr,
                   const int* __restrict__ col, const float* __restrict__ dinv,
                   const float* __restrict__ b3, float bscale,
                   const int* __restrict__ labels,
                   const unsigned short* __restrict__ W3pk,
                   const unsigned short* __restrict__ WcombP,
                   const float* __restrict__ whs, const float* __restrict__ bcomb,
                   float* __restrict__ outp, int m_total, int C, int n) {
    __shared__ uint4 Vs[16 * 17];
    __shared__ float Ds[16];
    __shared__ float Mred[8 * 16];
    __shared__ float Sred[8 * 16];
    __shared__ float Ls[16];
    int wid  = threadIdx.x >> 6;
    int lane = threadIdx.x & 63;
    int m = blockIdx.x * 16 + wid;
    bool valid = m < m_total;
    int node = valid ? labels[m] : 0;
    int beg = 0, end = 0;
    if (valid) { beg = row_ptr[node]; end = row_ptr[node + 1]; }
    float di = dinv[node];
    int qid = lane >> 4, fo = lane & 15;
    const uint4* h16 = (const uint4*)A;
    uint4 sd = h16[((unsigned)node << 4) | fo];
    float aL0 = 0.f, aH0 = 0.f, aL1 = 0.f, aH1 = 0.f;
    float aL2 = 0.f, aH2 = 0.f, aL3 = 0.f, aH3 = 0.f;
    float bL0 = 0.f, bH0 = 0.f, bL1 = 0.f, bH1 = 0.f;
    float bL2 = 0.f, bH2 = 0.f, bL3 = 0.f, bH3 = 0.f;
    int j = beg + qid;
    int s0 = (j < end) ? col[j] : n;         // dinv[n]=0, A row n zeros
    int s1 = (j + 4 < end) ? col[j + 4] : n;
    float w0 = dinv[s0], w1 = dinv[s1];
    while (s0 != n) {
        uint4 d0 = h16[((unsigned)s0 << 4) | fo];
        uint4 d1 = h16[((unsigned)s1 << 4) | fo];
        float cw0 = w0, cw1 = w1;
        int jn = j + 8;
        s0 = (jn < end) ? col[jn] : n;
        s1 = (jn + 4 < end) ? col[jn + 4] : n;
        w0 = dinv[s0]; w1 = dinv[s1];
        j = jn;
        aL0 = fmaf(cw0, bflo(d0.x), aL0); aH0 = fmaf(cw0, bfhi(d0.x), aH0);
        aL1 = fmaf(cw0, bflo(d0.y), aL1); aH1 = fmaf(cw0, bfhi(d0.y), aH1);
        aL2 = fmaf(cw0, bflo(d0.z), aL2); aH2 = fmaf(cw0, bfhi(d0.z), aH2);
        aL3 = fmaf(cw0, bflo(d0.w), aL3); aH3 = fmaf(cw0, bfhi(d0.w), aH3);
        bL0 = fmaf(cw1, bflo(d1.x), bL0); bH0 = fmaf(cw1, bfhi(d1.x), bH0);
        bL1 = fmaf(cw1, bflo(d1.y), bL1); bH1 = fmaf(cw1, bfhi(d1.y), bH1);
        bL2 = fmaf(cw1, bflo(d1.z), bL2); bH2 = fmaf(cw1, bfhi(d1.z), bH2);
        bL3 = fmaf(cw1, bflo(d1.w), bL3); bH3 = fmaf(cw1, bfhi(d1.w), bH3);
    }
    aL0 += bL0; aH0 += bH0; aL1 += bL1; aH1 += bH1;
    aL2 += bL2; aH2 += bH2; aL3 += bL3; aH3 += bH3;
    aL0 += __shfl_xor(aL0, 16, 64); aL0 += __shfl_xor(aL0, 32, 64);
    aH0 += __shfl_xor(aH0, 16, 64); aH0 += __shfl_xor(aH0, 32, 64);
    aL1 += __shfl_xor(aL1, 16, 64); aL1 += __shfl_xor(aL1, 32, 64);
    aH1 += __shfl_xor(aH1, 16, 64); aH1 += __shfl_xor(aH1, 32, 64);
    aL2 += __shfl_xor(aL2, 16, 64); aL2 += __shfl_xor(aL2, 32, 64);
    aH2 += __shfl_xor(aH2, 16, 64); aH2 += __shfl_xor(aH2, 32, 64);
    aL3 += __shfl_xor(aL3, 16, 64); aL3 += __shfl_xor(aL3, 32, 64);
    aH3 += __shfl_xor(aH3, 16, 64); aH3 += __shfl_xor(aH3, 32, 64);
    aL0 = fmaf(di, bflo(sd.x), aL0); aH0 = fmaf(di, bfhi(sd.x), aH0);
    aL1 = fmaf(di, bflo(sd.y), aL1); aH1 = fmaf(di, bfhi(sd.y), aH1);
    aL2 = fmaf(di, bflo(sd.z), aL2); aH2 = fmaf(di, bfhi(sd.z), aH2);
    aL3 = fmaf(di, bflo(sd.w), aL3); aH3 = fmaf(di, bfhi(sd.w), aH3);
    if (lane < 16) {
        uint4 o;
        o.x = pack_bf2(aL0, aH0);
        o.y = pack_bf2(aL1, aH1);
        o.z = pack_bf2(aL2, aH2);
        o.w = pack_bf2(aL3, aH3);
        Vs[wid * 17 + fo] = o;
    }
    if (lane == 0) Ds[wid] = di;
    __syncthreads();   // barrier 1: S staged

    f32x4 hacc = {0.f, 0.f, 0.f, 0.f};
    float cell[4] = {0.f, 0.f, 0.f, 0.f};
    float gmx[4]  = {0.f, 0.f, 0.f, 0.f};
    int mm = lane & 15, quad = lane >> 4;
    if (wid < 8) {
        int nt = wid;
        bf16x8 afr[4];
        #pragma unroll
        for (int kc = 0; kc < 4; ++kc) {
            U4B8 a; a.q = Vs[mm * 17 + kc * 4 + quad];
            afr[kc] = a.v;
        }
        f32x4 acc = {0.f, 0.f, 0.f, 0.f};
        const uint4* wp = (const uint4*)W3pk;
        #pragma unroll
        for (int kc = 0; kc < 4; ++kc) {
            U4B8 b; b.q = wp[(nt * 4 + kc) * 64 + lane];
            acc = __builtin_amdgcn_mfma_f32_16x16x32_bf16(afr[kc], b.v, acc, 0, 0, 0);
        }
        float b3c = bscale * b3[nt * 16 + mm];
        #pragma unroll
        for (int t = 0; t < 4; ++t) {
            int row = quad * 4 + t;
            cell[t] = fmaf(Ds[row], acc[t], b3c);
            float mxv = cell[t];
            #pragma unroll
            for (int off = 1; off < 16; off <<= 1)
                mxv = fmaxf(mxv, __shfl_xor(mxv, off, 64));
            if (mm == 0) Mred[nt * 16 + row] = mxv;
        }
    } else if (wid < 11) {
        int nth = wid - 8;
        bf16x8 afr[4];
        #pragma unroll
        for (int kc = 0; kc < 4; ++kc) {
            U4B8 a; a.q = Vs[mm * 17 + kc * 4 + quad];
            afr[kc] = a.v;
        }
        const uint4* wp = (const uint4*)WcombP;
        #pragma unroll
        for (int kc = 0; kc < 4; ++kc) {
            U4B8 b; b.q = wp[(nth * 4 + kc) * 64 + lane];
            hacc = __builtin_amdgcn_mfma_f32_16x16x32_bf16(afr[kc], b.v, hacc, 0, 0, 0);
        }
    }
    __syncthreads();   // barrier 2: Mred complete

    if (wid < 8) {
        int nt = wid;
        #pragma unroll
        for (int t = 0; t < 4; ++t) {
            int row = quad * 4 + t;
            float g = Mred[row];
            #pragma unroll
            for (int i = 1; i < 8; ++i) g = fmaxf(g, Mred[i * 16 + row]);
            gmx[t] = g;
            float e = expf(cell[t] - g);
            #pragma unroll
            for (int off = 1; off < 16; off <<= 1) e += __shfl_xor(e, off, 64);
            if (mm == 0) Sred[nt * 16 + row] = e;
        }
    }
    __syncthreads();   // barrier 3: Sred complete

    if (wid == 0 && mm == 0) {
        #pragma unroll
        for (int t = 0; t < 4; ++t) {
            int row = quad * 4 + t;
            float s = Sred[row];
            #pragma unroll
            for (int i = 1; i < 8; ++i) s += Sred[i * 16 + row];
            Ls[row] = gmx[t] + logf(s);
        }
    }
    __syncthreads();   // barrier 4: Ls ready

    if (wid >= 8 && wid < 11) {
        int nth = wid - 8;
        int colc = nth * 16 + mm;
        if (colc < C) {
            float wsc = whs[colc], bc = bcomb[colc];
            #pragma unroll
            for (int t = 0; t < 4; ++t) {
                int row = quad * 4 + t;
                int r = blockIdx.x * 16 + row;
                if (r < m_total)
                    outp[(size_t)r * C + colc] =
                        fmaf(Ds[row], hacc[t], bc) - Ls[row] * wsc;
            }
        }
    }
}

// ---------------------------------------------------------------------------
extern "C" void kernel_launch(void* const* d_in, const int* in_sizes, int n_in,
                              void* d_out, int out_size, void* d_ws, size_t ws_size,
                              hipStream_t stream) {
    const float* x      = (const float*)d_in[0];
    const int*   edges  = (const int*)d_in[1];
    const int*   labels = (const int*)d_in[2];
    const float* W0 = (const float*)d_in[3];
    const float* b0 = (const float*)d_in[4];
    const float* W1 = (const float*)d_in[5];
    const float* b1 = (const float*)d_in[6];
    const float* W2 = (const float*)d_in[7];
    const float* b2 = (const float*)d_in[8];
    const float* W3 = (const float*)d_in[9];
    const float* b3 = (const float*)d_in[10];
    const float* Wh = (const float*)d_in[11];
    const float* bh = (const float*)d_in[12];
    float* out = (float*)d_out;

    const int N = in_sizes[0] / DIM;       // 50000
    const int E = in_sizes[1] / 2;         // 600000
    const int M = in_sizes[2];             // 25000
    const int C = in_sizes[12];            // 40

    // Workspace layout (256B-aligned slices)
    char* ws = (char*)d_ws;
    auto alloc = [&](size_t bytes) {
        char* p = ws;
        ws += (bytes + 255) & ~(size_t)255;
        return p;
    };
    float* dinv    = (float*)alloc((size_t)(N + 1) * 4);   // +1: sentinel weight 0
    int*   count   = (int*)  alloc((size_t)N * 4);
    int*   row_ptr = (int*)  alloc((size_t)(N + 1) * 4);
    int*   rank    = (int*)  alloc((size_t)E * 4);
    int*   bsum    = (int*)  alloc(64 * 4);
    int*   col     = (int*)  alloc((size_t)E * 4);
    float* whs     = (float*)alloc(256);
    float* bcomb   = (float*)alloc(256);
    unsigned short* Wpk    = (unsigned short*)alloc((size_t)4 * DIM * DIM * 2);  // packed W0..3
    unsigned short* WcombP = (unsigned short*)alloc((size_t)3 * 4 * 64 * 8 * 2); // packed W3@Wh
    unsigned short* H   = (unsigned short*)alloc((size_t)(N + 1) * DIM * 2);  // bf16 ping + sentinel
    unsigned short* H2  = (unsigned short*)alloc((size_t)(N + 1) * DIM * 2);  // bf16 pong + sentinel
    unsigned short* R0  = (unsigned short*)alloc((size_t)N * DIM * 2);        // relu(cell0) bf16
    unsigned short* A   = (unsigned short*)alloc((size_t)(N + 1) * DIM * 2);  // running relu-sum + sentinel

    const int* src = edges;
    const int* dst = edges + E;

    int egrid  = (E + 255) / 256;
    int sgrid  = (N + 1023) / 1024;        // scan blocks (49 for N=50000)
    int mmgrid = (N + 63) / 64;            // 64-row strips, 4 waves/block
    int pgrid  = (N + 3) / 4;              // one wave per node, 4 waves/block
    int fgrid  = (N + 15) / 16;            // fused prop+mm blocks (16 nodes each)
    const int FR = DIM * DIM;              // per-matrix packed elements
    const int NPACK = 4 * FR + 3 * 4 * 64 * 8 + 64 + 113;
    int packgrid = (NPACK + 255) / 256;

    // --- CSR build + weight packing (count+rank || pack, fill || matmul0) ---
    hipMemsetAsync(count, 0, (size_t)N * 4, stream);
    k_init <<<egrid + packgrid, 256, 0, stream>>>(dst, count, rank, E, egrid,
                                                  W0, W1, W2, W3, Wh, b3, bh,
                                                  Wpk, WcombP, whs, bcomb,
                                                  H, H2, A, dinv, bsum, N, C);
    k_scan <<<sgrid, 1024, 0, stream>>>(count, bsum, row_ptr, dinv, N, sgrid);
    k_fillmm<<<mmgrid + egrid, 256, 0, stream>>>(x, Wpk, dinv, H, N,
                                                 src, dst, rank, row_ptr, col, E, mmgrid);
    // --- P0: R0 = relu(Â(xW0)+b0); fused mm1 -> H2 = dinv*(R0@W1) ---
    k_prop_mm<<<fgrid, 1024, 0, stream>>>(H, row_ptr, col, dinv, b0, 1.f,
                                          nullptr, R0, Wpk + 1 * FR, H2, N);
    // --- P1: A = R0 + relu(Â(R0W1)+b1); fused mm2 -> H = dinv*(A@W2) ---
    k_prop_mm<<<fgrid, 1024, 0, stream>>>(H2, row_ptr, col, dinv, b1, 1.f,
                                          R0, A, Wpk + 2 * FR, H, N);
    // --- P2: A += relu(Â(AW2)+2b2)  (in-place row-local, no trailing mm) ---
    k_prop    <<<pgrid, 256, 0, stream>>>(H, row_ptr, col, dinv, b2, 2.f, A, A, N);
    // --- layer-3 commute: gather A directly (weighted), matmul only M rows ---
    k_propv_fused<<<(M + 15) / 16, 1024, 0, stream>>>(A, row_ptr, col, dinv, b3, 3.f,
                                                      labels, Wpk + 3 * FR, WcombP,
                                                      whs, bcomb, out, M, C, N);
}